// Round 1
// baseline (179.258 us; speedup 1.0000x reference)
//
#include <hip/hip_runtime.h>
#include <hip/hip_bf16.h>
#include <stdint.h>

// GCN fused: out = relu(A @ (H @ W^T) + b)
// B=8, N=2048, L=4, D=256.  Reassociated so the linear layer is applied to H
// (8.6 GF) instead of to A@H, and the 68.7 GF batched GEMM writes d_out directly.

typedef __bf16 bf16;
typedef __attribute__((ext_vector_type(8))) __bf16 bf16x8;
typedef __attribute__((ext_vector_type(4))) __bf16 bf16x4;
typedef __attribute__((ext_vector_type(4))) float f32x4;

#define B_  8
#define N_  2048
#define L_  4
#define D_  256
#define LD_ 1024

#define GLOAD_LDS16(g, l) __builtin_amdgcn_global_load_lds(                 \
    (const __attribute__((address_space(1))) void*)(g),                     \
    (__attribute__((address_space(3))) void*)(l), 16, 0, 0)

// convert 8 consecutive floats -> 8 bf16, store 16B
__device__ inline void cvt_store8(const float* __restrict__ s, bf16* d) {
  float4 x = ((const float4*)s)[0];
  float4 y = ((const float4*)s)[1];
  bf16x8 o;
  o[0] = (bf16)x.x; o[1] = (bf16)x.y; o[2] = (bf16)x.z; o[3] = (bf16)x.w;
  o[4] = (bf16)y.x; o[5] = (bf16)y.y; o[6] = (bf16)y.z; o[7] = (bf16)y.w;
  *(bf16x8*)d = o;
}

// ---------------- kernel 1: A fp32 -> bf16 (elementwise) ----------------
__global__ __launch_bounds__(256) void cvt_a_kernel(const float* __restrict__ src,
                                                    bf16* __restrict__ dst, int n8) {
  int i = blockIdx.x * 256 + threadIdx.x;
  const int stride = gridDim.x * 256;
  for (; i < n8; i += stride) {
    const float4* s = (const float4*)src + (size_t)i * 2;
    float4 x = s[0], y = s[1];
    bf16x8 o;
    o[0] = (bf16)x.x; o[1] = (bf16)x.y; o[2] = (bf16)x.z; o[3] = (bf16)x.w;
    o[4] = (bf16)y.x; o[5] = (bf16)y.y; o[6] = (bf16)y.z; o[7] = (bf16)y.w;
    *(bf16x8*)(dst + (size_t)i * 8) = o;
  }
}

// ---------------- kernel 2: HWT_T[b][l*256+e][m] = sum_d H[b][m][l][d]*W[e][d] ----
// Stored TRANSPOSED (cols = m, contiguous) so GEMM-1's B operand is k-contiguous.
// Trick: A-tile rows are permuted in LDS as q = l*32 + m_local so the MFMA C
// fragment's 4 consecutive rows (per lane) are m-contiguous -> 8B packed stores.
__global__ __launch_bounds__(256) void hwt_kernel(const float* __restrict__ H,
                                                  const float* __restrict__ Wm,
                                                  bf16* __restrict__ outT) {
  const int bid = blockIdx.x;          // 8 * 64 * 2 = 1024 blocks
  const int b   = bid >> 7;
  const int rem = bid & 127;
  const int te  = rem & 1;
  const int tr  = rem >> 1;
  const int r0  = tr * 128;            // row base in the 8192-row H[b] slab
  const int e0  = te * 128;

  __shared__ __attribute__((aligned(16))) bf16 Ah[128 * 64];
  __shared__ __attribute__((aligned(16))) bf16 Wt[128 * 64];

  const int t    = threadIdx.x;
  const int lane = t & 63;
  const int wave = t >> 6;
  const int wr = wave >> 1, wc = wave & 1;   // 2x2 waves, 64x64 each

  const f32x4 zero = {0.f, 0.f, 0.f, 0.f};
  f32x4 acc[4][4];
  for (int m = 0; m < 4; ++m)
    for (int n = 0; n < 4; ++n) acc[m][n] = zero;

  const float* Hb = H + (size_t)b * (N_ * L_ * D_);
  const int mrow = t >> 3;          // 0..31
  const int colb = (t & 7) * 8;     // 0..56

  for (int k0 = 0; k0 < D_; k0 += 64) {
#pragma unroll
    for (int i = 0; i < 4; ++i) {
      // LDS row q = i*32 + mrow  holds H row r = mrow*4 + i  (l = i, m_local = mrow)
      const int r_local = mrow * 4 + i;
      cvt_store8(Hb + (size_t)(r0 + r_local) * D_ + k0 + colb,
                 Ah + (size_t)t * 8 + i * 2048);
      const int erow = i * 32 + mrow;
      cvt_store8(Wm + (size_t)(e0 + erow) * D_ + k0 + colb,
                 Wt + (size_t)t * 8 + i * 2048);
    }
    __syncthreads();
#pragma unroll
    for (int kk = 0; kk < 2; ++kk) {
      bf16x8 af[4], bg[4];
#pragma unroll
      for (int m = 0; m < 4; ++m)
        af[m] = *(const bf16x8*)&Ah[(wr * 64 + m * 16 + (lane & 15)) * 64 + kk * 32 + (lane >> 4) * 8];
#pragma unroll
      for (int n = 0; n < 4; ++n)
        bg[n] = *(const bf16x8*)&Wt[(wc * 64 + n * 16 + (lane & 15)) * 64 + kk * 32 + (lane >> 4) * 8];
#pragma unroll
      for (int m = 0; m < 4; ++m)
#pragma unroll
        for (int n = 0; n < 4; ++n)
          acc[m][n] = __builtin_amdgcn_mfma_f32_16x16x32_bf16(af[m], bg[n], acc[m][n], 0, 0, 0);
    }
    __syncthreads();
  }

  // epilogue: C row q -> (l = q>>5, m_local = q&31); 4 rows/lane are m-contiguous
  bf16* ob = outT + (size_t)b * (LD_ * N_);
  const int m0 = tr * 32;
#pragma unroll
  for (int m16 = 0; m16 < 4; ++m16) {
    const int qrow = wr * 64 + m16 * 16 + ((lane >> 4) << 2);
    const int l  = qrow >> 5;
    const int ml = qrow & 31;
#pragma unroll
    for (int n = 0; n < 4; ++n) {
      const int e = e0 + wc * 64 + n * 16 + (lane & 15);
      bf16x4 v;
      v[0] = (bf16)acc[m16][n][0]; v[1] = (bf16)acc[m16][n][1];
      v[2] = (bf16)acc[m16][n][2]; v[3] = (bf16)acc[m16][n][3];
      *(bf16x4*)&ob[(size_t)(l * 256 + e) * N_ + m0 + ml] = v;
    }
  }
}

// ---------------- kernel 3: out[b][n][c] = relu(sum_m A[b][n][m]*HWT_T[b][c][m] + bias[c&255])
// m97-style 128x128 tile, BK=64, 4 waves, global_load_lds staging, linear LDS.
// CONV=true: A staged from fp32 with on-the-fly bf16 convert (small-ws fallback).
template <bool CONV>
__global__ __launch_bounds__(256) void gemm1_kernel(const bf16* __restrict__ A16,
                                                    const float* __restrict__ Af32,
                                                    const bf16* __restrict__ HWT,
                                                    const float* __restrict__ bias,
                                                    float* __restrict__ out) {
  const int bid = blockIdx.x;          // 8 * 16 * 8 = 1024 blocks
  const int b   = bid >> 7;
  const int rem = bid & 127;
  const int tc  = rem & 7;             // c fast: 8 consecutive blocks share A rows
  const int tn  = rem >> 3;
  const int n0  = tn * 128;
  const int c0  = tc * 128;

  __shared__ __attribute__((aligned(16))) bf16 As[128 * 64];
  __shared__ __attribute__((aligned(16))) bf16 Bs[128 * 64];

  const int t    = threadIdx.x;
  const int lane = t & 63;
  const int wave = t >> 6;
  const int wr = wave >> 1, wc = wave & 1;

  const f32x4 zero = {0.f, 0.f, 0.f, 0.f};
  f32x4 acc[4][4];
  for (int m = 0; m < 4; ++m)
    for (int n = 0; n < 4; ++n) acc[m][n] = zero;

  const bf16*  Ab = A16 + (size_t)b * N_ * N_;
  const float* Af = Af32 + (size_t)b * N_ * N_;
  const bf16*  Hb = HWT + (size_t)b * LD_ * N_;

  const int mrow = t >> 3;
  const int colb = (t & 7) * 8;

  for (int k0 = 0; k0 < N_; k0 += 64) {
    if constexpr (CONV) {
#pragma unroll
      for (int i = 0; i < 4; ++i) {
        const int row = i * 32 + mrow;
        cvt_store8(Af + (size_t)(n0 + row) * N_ + k0 + colb,
                   As + (size_t)t * 8 + i * 2048);
      }
    } else {
#pragma unroll
      for (int i = 0; i < 4; ++i) {
        const int row = i * 32 + mrow;
        GLOAD_LDS16(Ab + (size_t)(n0 + row) * N_ + k0 + colb,
                    (char*)As + t * 16 + i * 4096);
      }
    }
#pragma unroll
    for (int i = 0; i < 4; ++i) {
      const int row = i * 32 + mrow;
      GLOAD_LDS16(Hb + (size_t)(c0 + row) * N_ + k0 + colb,
                  (char*)Bs + t * 16 + i * 4096);
    }
    __syncthreads();
#pragma unroll
    for (int kk = 0; kk < 2; ++kk) {
      bf16x8 af[4], bg[4];
#pragma unroll
      for (int m = 0; m < 4; ++m)
        af[m] = *(const bf16x8*)&As[(wr * 64 + m * 16 + (lane & 15)) * 64 + kk * 32 + (lane >> 4) * 8];
#pragma unroll
      for (int n = 0; n < 4; ++n)
        bg[n] = *(const bf16x8*)&Bs[(wc * 64 + n * 16 + (lane & 15)) * 64 + kk * 32 + (lane >> 4) * 8];
#pragma unroll
      for (int m = 0; m < 4; ++m)
#pragma unroll
        for (int n = 0; n < 4; ++n)
          acc[m][n] = __builtin_amdgcn_mfma_f32_16x16x32_bf16(af[m], bg[n], acc[m][n], 0, 0, 0);
    }
    __syncthreads();
  }

  // epilogue: + bias, relu, fp32 store (16 lanes x 4B contiguous -> 64B lines)
  float* ob = out + (size_t)b * N_ * LD_;
#pragma unroll
  for (int m = 0; m < 4; ++m) {
    const int row = n0 + wr * 64 + m * 16 + ((lane >> 4) << 2);
#pragma unroll
    for (int n = 0; n < 4; ++n) {
      const int c = c0 + wc * 64 + n * 16 + (lane & 15);
      const float bv = bias[c & 255];
#pragma unroll
      for (int j = 0; j < 4; ++j) {
        float v = acc[m][n][j] + bv;
        ob[(size_t)(row + j) * LD_ + c] = v > 0.f ? v : 0.f;
      }
    }
  }
}

extern "C" void kernel_launch(void* const* d_in, const int* in_sizes, int n_in,
                              void* d_out, int out_size, void* d_ws, size_t ws_size,
                              hipStream_t stream) {
  const float* H    = (const float*)d_in[0];   // prop_state (B,N,L,D)
  const float* A    = (const float*)d_in[1];   // (B,N,N)
  const float* Wm   = (const float*)d_in[2];   // (D,D)
  const float* bias = (const float*)d_in[3];   // (D,)
  float* out = (float*)d_out;

  const size_t hwt_bytes = (size_t)B_ * LD_ * N_ * sizeof(bf16);  // 33.5 MB
  const size_t a16_bytes = (size_t)B_ * N_ * N_ * sizeof(bf16);   // 67.1 MB

  if (ws_size < hwt_bytes) return;  // cannot run safely; leave output poisoned

  bf16* hwt = (bf16*)d_ws;
  bf16* a16 = (bf16*)((char*)d_ws + hwt_bytes);

  hwt_kernel<<<dim3(1024), dim3(256), 0, stream>>>(H, Wm, hwt);

  if (ws_size >= hwt_bytes + a16_bytes) {
    cvt_a_kernel<<<dim3(2048), dim3(256), 0, stream>>>(A, a16,
        (int)((size_t)B_ * N_ * N_ / 8));
    gemm1_kernel<false><<<dim3(1024), dim3(256), 0, stream>>>(a16, A, hwt, bias, out);
  } else {
    gemm1_kernel<true><<<dim3(1024), dim3(256), 0, stream>>>((const bf16*)nullptr, A, hwt, bias, out);
  }
}

// Round 2
// 138.254 us; speedup vs baseline: 1.2966x; 1.2966x over previous
//
#include <hip/hip_runtime.h>
#include <hip/hip_bf16.h>
#include <stdint.h>

// GCN fused: out = relu(A @ (H @ W^T) + b),  B=8, N=2048, L=4, D=256.
// Reassociated: HWT = H@W^T (small GEMM, bf16, stored k-contiguous/transposed),
// then one 68.7 GF batched GEMM A@HWT with bias+relu epilogue -> d_out.
// Main GEMM: 256x256 tile, BK=64, 8 waves, 8-phase counted-vmcnt pipeline
// (T3+T4), LDS slot-XOR swizzle (T2), setprio around MFMA (T5), XCD=batch (T1).

typedef __bf16 bf16;
typedef __attribute__((ext_vector_type(8))) __bf16 bf16x8;
typedef __attribute__((ext_vector_type(4))) __bf16 bf16x4;
typedef __attribute__((ext_vector_type(4))) float f32x4;

#define B_  8
#define N_  2048
#define L_  4
#define D_  256
#define LD_ 1024
#define BK  64
#define NT  (N_ / BK)   // 32 K-tiles
#define NI  (NT / 2)    // 16 iterations

__device__ __forceinline__ void gl16(const char* g, char* l) {
  __builtin_amdgcn_global_load_lds((const __attribute__((address_space(1))) void*)g,
                                   (__attribute__((address_space(3))) void*)l, 16, 0, 0);
}

// convert 8 consecutive floats -> 8 bf16, store 16B
__device__ inline void cvt_store8(const float* __restrict__ s, bf16* d) {
  float4 x = ((const float4*)s)[0];
  float4 y = ((const float4*)s)[1];
  bf16x8 o;
  o[0] = (bf16)x.x; o[1] = (bf16)x.y; o[2] = (bf16)x.z; o[3] = (bf16)x.w;
  o[4] = (bf16)y.x; o[5] = (bf16)y.y; o[6] = (bf16)y.z; o[7] = (bf16)y.w;
  *(bf16x8*)d = o;
}

// ---------------- kernel 1: A fp32 -> bf16 ----------------
__global__ __launch_bounds__(256) void cvt_a_kernel(const float* __restrict__ src,
                                                    bf16* __restrict__ dst, int n8) {
  int i = blockIdx.x * 256 + threadIdx.x;
  const int stride = gridDim.x * 256;
  for (; i < n8; i += stride) {
    const float4* s = (const float4*)src + (size_t)i * 2;
    float4 x = s[0], y = s[1];
    bf16x8 o;
    o[0] = (bf16)x.x; o[1] = (bf16)x.y; o[2] = (bf16)x.z; o[3] = (bf16)x.w;
    o[4] = (bf16)y.x; o[5] = (bf16)y.y; o[6] = (bf16)y.z; o[7] = (bf16)y.w;
    *(bf16x8*)(dst + (size_t)i * 8) = o;
  }
}

// ---------------- kernel 2: HWT_T[b][l*256+e][m] = sum_d H[b][m][l][d]*W[e][d] ----
__global__ __launch_bounds__(256) void hwt_kernel(const float* __restrict__ H,
                                                  const float* __restrict__ Wm,
                                                  bf16* __restrict__ outT) {
  const int bid = blockIdx.x;          // 8 * 64 * 2 = 1024 blocks
  const int b   = bid >> 7;
  const int rem = bid & 127;
  const int te  = rem & 1;
  const int tr  = rem >> 1;
  const int r0  = tr * 128;
  const int e0  = te * 128;

  __shared__ __attribute__((aligned(16))) bf16 Ah[128 * 64];
  __shared__ __attribute__((aligned(16))) bf16 Wt[128 * 64];

  const int t    = threadIdx.x;
  const int lane = t & 63;
  const int wave = t >> 6;
  const int wr = wave >> 1, wc = wave & 1;

  const f32x4 zero = {0.f, 0.f, 0.f, 0.f};
  f32x4 acc[4][4];
  for (int m = 0; m < 4; ++m)
    for (int n = 0; n < 4; ++n) acc[m][n] = zero;

  const float* Hb = H + (size_t)b * (N_ * L_ * D_);
  const int mrow = t >> 3;
  const int colb = (t & 7) * 8;

  for (int k0 = 0; k0 < D_; k0 += 64) {
#pragma unroll
    for (int i = 0; i < 4; ++i) {
      const int r_local = mrow * 4 + i;     // l = i, m_local = mrow
      cvt_store8(Hb + (size_t)(r0 + r_local) * D_ + k0 + colb,
                 Ah + (size_t)t * 8 + i * 2048);
      const int erow = i * 32 + mrow;
      cvt_store8(Wm + (size_t)(e0 + erow) * D_ + k0 + colb,
                 Wt + (size_t)t * 8 + i * 2048);
    }
    __syncthreads();
#pragma unroll
    for (int kk = 0; kk < 2; ++kk) {
      bf16x8 af[4], bg[4];
#pragma unroll
      for (int m = 0; m < 4; ++m)
        af[m] = *(const bf16x8*)&Ah[(wr * 64 + m * 16 + (lane & 15)) * 64 + kk * 32 + (lane >> 4) * 8];
#pragma unroll
      for (int n = 0; n < 4; ++n)
        bg[n] = *(const bf16x8*)&Wt[(wc * 64 + n * 16 + (lane & 15)) * 64 + kk * 32 + (lane >> 4) * 8];
#pragma unroll
      for (int m = 0; m < 4; ++m)
#pragma unroll
        for (int n = 0; n < 4; ++n)
          acc[m][n] = __builtin_amdgcn_mfma_f32_16x16x32_bf16(af[m], bg[n], acc[m][n], 0, 0, 0);
    }
    __syncthreads();
  }

  bf16* ob = outT + (size_t)b * (LD_ * N_);
  const int m0 = tr * 32;
#pragma unroll
  for (int m16 = 0; m16 < 4; ++m16) {
    const int qrow = wr * 64 + m16 * 16 + ((lane >> 4) << 2);
    const int l  = qrow >> 5;
    const int ml = qrow & 31;
#pragma unroll
    for (int n = 0; n < 4; ++n) {
      const int e = e0 + wc * 64 + n * 16 + (lane & 15);
      bf16x4 v;
      v[0] = (bf16)acc[m16][n][0]; v[1] = (bf16)acc[m16][n][1];
      v[2] = (bf16)acc[m16][n][2]; v[3] = (bf16)acc[m16][n][3];
      *(bf16x4*)&ob[(size_t)(l * 256 + e) * N_ + m0 + ml] = v;
    }
  }
}

// ---------------- kernel 3: 256x256-tile 8-phase GEMM ----------------
// out[b][n][c] = relu(sum_m A16[b][n][m] * HWT[b][c][m] + bias[c&255])
__global__ __launch_bounds__(512, 2) void gemm8p_kernel(
    const bf16* __restrict__ A16, const bf16* __restrict__ HWT,
    const float* __restrict__ bias, float* __restrict__ out) {

  __shared__ __attribute__((aligned(128))) char smem[131072];

  // T1: XCD-aware swizzle; 256 blocks % 8 == 0 -> xcd = batch
  const int bid = blockIdx.x;
  const int lg  = (bid & 7) * 32 + (bid >> 3);
  const int b   = lg >> 5;
  const int tn  = (lg >> 2) & 7;   // M tile (output rows, n-dim)
  const int tc  = lg & 3;          // N tile (output cols, c-dim)
  const int n0  = tn * 256;
  const int c0  = tc * 256;

  const int t    = threadIdx.x;
  const int lane = t & 63;
  const int w    = t >> 6;
  const int wm   = w >> 2;   // 0..1
  const int wn   = w & 3;    // 0..3
  const int l15  = lane & 15;
  const int cg   = lane >> 4;
  const int sl0  = cg ^ (lane & 7);     // swizzled 16B-slot for kk=0

  const char* Ab = (const char*)(A16 + (size_t)b * N_ * N_);
  const char* Hb = (const char*)(HWT + (size_t)b * LD_ * N_);
  const int  grow  = t >> 3;                       // 0..63
  const int  gslot = ((t & 7) ^ (grow & 7)) << 4;  // pre-swizzled source slot
  const char* pA = Ab + (size_t)(n0 + grow) * (N_ * 2) + gslot;
  const char* pB = Hb + (size_t)(c0 + grow) * (N_ * 2) + gslot;
  char* lbase = (char*)smem + t * 16;

#define STAGE(buf, isB, half, kt) do {                                        \
    const char* gp_ = ((isB) ? pB : pA) + (size_t)((half) * 128) * (N_ * 2)   \
                      + (size_t)(kt) * (BK * 2);                              \
    char* lp_ = lbase + (buf) * 65536 + (isB) * 32768 + (half) * 16384;       \
    gl16(gp_, lp_);                                                           \
    gl16(gp_ + (size_t)64 * (N_ * 2), lp_ + 8192);                            \
  } while (0)

#define LDA(buf, mh, fm, kk)                                                  \
  (*(const bf16x8*)(smem + (buf) * 65536 +                                    \
      (wm * 128 + (mh) * 64 + (fm) * 16 + l15) * 128 +                        \
      ((sl0 ^ ((kk) * 4)) << 4)))

#define LDB(buf, fn, kk)                                                      \
  (*(const bf16x8*)(smem + (buf) * 65536 + 32768 +                            \
      (wn * 64 + (fn) * 16 + l15) * 128 +                                     \
      ((sl0 ^ ((kk) * 4)) << 4)))

#define MFMA16(mh, kkid, AF)                                                  \
  _Pragma("unroll")                                                           \
  for (int fm_ = 0; fm_ < 4; ++fm_)                                           \
    _Pragma("unroll")                                                         \
    for (int fn_ = 0; fn_ < 4; ++fn_)                                         \
      acc[(mh) * 4 + fm_][fn_] = __builtin_amdgcn_mfma_f32_16x16x32_bf16(     \
          AF[fm_], bfr[kkid][fn_], acc[(mh) * 4 + fm_][fn_], 0, 0, 0);

#define BARRIER() do { __builtin_amdgcn_s_barrier();                          \
                       asm volatile("" ::: "memory"); } while (0)
#define WAIT_LGKM0() do {                                                     \
    asm volatile("s_waitcnt lgkmcnt(0)" ::: "memory");                        \
    __builtin_amdgcn_sched_barrier(0); } while (0)
#define MFMA_PHASE(mh, kkid, AF) do {                                         \
    __builtin_amdgcn_s_setprio(1);                                            \
    MFMA16(mh, kkid, AF);                                                     \
    __builtin_amdgcn_s_setprio(0);                                            \
    __builtin_amdgcn_sched_barrier(0);                                        \
    BARRIER(); } while (0)

  f32x4 acc[8][4];
#pragma unroll
  for (int i_ = 0; i_ < 8; ++i_)
#pragma unroll
    for (int j_ = 0; j_ < 4; ++j_) acc[i_][j_] = (f32x4){0.f, 0.f, 0.f, 0.f};

  bf16x8 bfr[2][4], a0[4], a1[4];

  // prologue: buf0 <- Ktile0 (4 halves), buf1 <- Ktile1 {B0,B1,A0}; 14 loads,
  // vmcnt(6) retires buf0's 8, leaves buf1's 6 in flight (steady-state entry).
  STAGE(0, 0, 0, 0); STAGE(0, 0, 1, 0); STAGE(0, 1, 0, 0); STAGE(0, 1, 1, 0);
  STAGE(1, 1, 0, 1); STAGE(1, 1, 1, 1); STAGE(1, 0, 0, 1);
  asm volatile("s_waitcnt vmcnt(6)" ::: "memory");
  __builtin_amdgcn_sched_barrier(0);
  BARRIER();

#pragma unroll 1
  for (int i = 0; i < NI; ++i) {
    const int ktA1 = 2 * i + 1;
    const int kt0  = (2 * i + 2 < NT) ? 2 * i + 2 : NT - 1;  // clamp keeps vmcnt uniform
    const int kt1  = (2 * i + 3 < NT) ? 2 * i + 3 : NT - 1;

    // P1: ds-read buf0 A(mh0,kk0) + B(all 2kk); stage buf1.A1 <- 2i+1
#pragma unroll
    for (int fm = 0; fm < 4; ++fm) a0[fm] = LDA(0, 0, fm, 0);
#pragma unroll
    for (int fn = 0; fn < 4; ++fn) bfr[0][fn] = LDB(0, fn, 0);
#pragma unroll
    for (int fn = 0; fn < 4; ++fn) bfr[1][fn] = LDB(0, fn, 1);
    STAGE(1, 0, 1, ktA1);
    asm volatile("s_waitcnt lgkmcnt(8)" ::: "memory");
    BARRIER();
    WAIT_LGKM0();
    MFMA_PHASE(0, 0, a0);

    // P2: ds-read A(mh0,kk1); stage buf0.B0 <- kt0
#pragma unroll
    for (int fm = 0; fm < 4; ++fm) a1[fm] = LDA(0, 0, fm, 1);
    STAGE(0, 1, 0, kt0);
    BARRIER();
    WAIT_LGKM0();
    MFMA_PHASE(0, 1, a1);

    // P3: ds-read A(mh1,kk0)+A(mh1,kk1); stage buf0.B1 <- kt0
#pragma unroll
    for (int fm = 0; fm < 4; ++fm) a0[fm] = LDA(0, 1, fm, 0);
#pragma unroll
    for (int fm = 0; fm < 4; ++fm) a1[fm] = LDA(0, 1, fm, 1);
    STAGE(0, 1, 1, kt0);
    BARRIER();
    WAIT_LGKM0();
    MFMA_PHASE(1, 0, a0);

    // P4: stage buf0.A0 <- kt0; counted vmcnt (retires buf1's 4 halves)
    STAGE(0, 0, 0, kt0);
    asm volatile("s_waitcnt vmcnt(6)" ::: "memory");
    __builtin_amdgcn_sched_barrier(0);
    BARRIER();
    MFMA_PHASE(1, 1, a1);

    // P5: ds-read buf1 A(mh0,kk0) + B(all); stage buf0.A1 <- kt0
#pragma unroll
    for (int fm = 0; fm < 4; ++fm) a0[fm] = LDA(1, 0, fm, 0);
#pragma unroll
    for (int fn = 0; fn < 4; ++fn) bfr[0][fn] = LDB(1, fn, 0);
#pragma unroll
    for (int fn = 0; fn < 4; ++fn) bfr[1][fn] = LDB(1, fn, 1);
    STAGE(0, 0, 1, kt0);
    asm volatile("s_waitcnt lgkmcnt(8)" ::: "memory");
    BARRIER();
    WAIT_LGKM0();
    MFMA_PHASE(0, 0, a0);

    // P6: ds-read buf1 A(mh0,kk1); stage buf1.B0 <- kt1
#pragma unroll
    for (int fm = 0; fm < 4; ++fm) a1[fm] = LDA(1, 0, fm, 1);
    STAGE(1, 1, 0, kt1);
    BARRIER();
    WAIT_LGKM0();
    MFMA_PHASE(0, 1, a1);

    // P7: ds-read buf1 A(mh1,*); stage buf1.B1 <- kt1
#pragma unroll
    for (int fm = 0; fm < 4; ++fm) a0[fm] = LDA(1, 1, fm, 0);
#pragma unroll
    for (int fm = 0; fm < 4; ++fm) a1[fm] = LDA(1, 1, fm, 1);
    STAGE(1, 1, 1, kt1);
    BARRIER();
    WAIT_LGKM0();
    MFMA_PHASE(1, 0, a0);

    // P8: stage buf1.A0 <- kt1; counted vmcnt (retires buf0's 4 halves)
    STAGE(1, 0, 0, kt1);
    asm volatile("s_waitcnt vmcnt(6)" ::: "memory");
    __builtin_amdgcn_sched_barrier(0);
    BARRIER();
    MFMA_PHASE(1, 1, a1);
  }

  // epilogue: + bias, relu, fp32 store
  float* ob = out + (size_t)b * N_ * LD_;
  const int orow0 = n0 + wm * 128 + cg * 4;
  const int ocol0 = c0 + wn * 64 + l15;
#pragma unroll
  for (int mh = 0; mh < 2; ++mh)
#pragma unroll
    for (int fm = 0; fm < 4; ++fm) {
      const int r = orow0 + mh * 64 + fm * 16;
#pragma unroll
      for (int fn = 0; fn < 4; ++fn) {
        const int c = ocol0 + fn * 16;
        const float bv = bias[c & 255];
        const f32x4 v = acc[mh * 4 + fm][fn];
#pragma unroll
        for (int j = 0; j < 4; ++j) {
          const float x = v[j] + bv;
          ob[(size_t)(r + j) * LD_ + c] = x > 0.f ? x : 0.f;
        }
      }
    }
#undef STAGE
#undef LDA
#undef LDB
#undef MFMA16
#undef MFMA_PHASE
#undef BARRIER
#undef WAIT_LGKM0
}

extern "C" void kernel_launch(void* const* d_in, const int* in_sizes, int n_in,
                              void* d_out, int out_size, void* d_ws, size_t ws_size,
                              hipStream_t stream) {
  const float* H    = (const float*)d_in[0];   // prop_state (B,N,L,D)
  const float* A    = (const float*)d_in[1];   // (B,N,N)
  const float* Wm   = (const float*)d_in[2];   // (D,D)
  const float* bias = (const float*)d_in[3];   // (D,)
  float* out = (float*)d_out;

  const size_t hwt_bytes = (size_t)B_ * LD_ * N_ * sizeof(bf16);  // 33.5 MB
  const size_t a16_bytes = (size_t)B_ * N_ * N_ * sizeof(bf16);   // 67.1 MB
  if (ws_size < hwt_bytes + a16_bytes) return;  // ws proven sufficient in R1

  bf16* hwt = (bf16*)d_ws;
  bf16* a16 = (bf16*)((char*)d_ws + hwt_bytes);

  hwt_kernel<<<dim3(1024), dim3(256), 0, stream>>>(H, Wm, hwt);
  cvt_a_kernel<<<dim3(2048), dim3(256), 0, stream>>>(A, a16,
      (int)((size_t)B_ * N_ * N_ / 8));
  gemm8p_kernel<<<dim3(256), dim3(512), 0, stream>>>(a16, hwt, bias, out);
}

// Round 3
// 132.119 us; speedup vs baseline: 1.3568x; 1.0464x over previous
//
#include <hip/hip_runtime.h>
#include <hip/hip_bf16.h>
#include <stdint.h>

// GCN fused: out = relu(A @ (H @ W^T) + b),  B=8, N=2048, L=4, D=256.
// pre_kernel: (blocks 0-1023) HWT = H@W^T bf16 transposed; (1024-3071) A->bf16.
// gemm8p: 256x256 tile, BK=64, 8 waves, software-pipelined 8-phase loop:
//   phase p issues ds_reads for MFMA p+1 (register double-buffer aX/aY,b0/b1),
//   compiler emits counted lgkm waits from dataflow; 4 barriers/iter
//   (P3/P7: vmcnt(0)+BAR gate buf RAW; P4/P8: BAR gates buf re-stage WAR).

typedef __bf16 bf16;
typedef __attribute__((ext_vector_type(8))) __bf16 bf16x8;
typedef __attribute__((ext_vector_type(4))) __bf16 bf16x4;
typedef __attribute__((ext_vector_type(4))) float f32x4;

#define B_  8
#define N_  2048
#define L_  4
#define D_  256
#define LD_ 1024
#define BK  64
#define NT  (N_ / BK)   // 32 K-tiles
#define NI  (NT / 2)    // 16 iterations

__device__ __forceinline__ void gl16(const char* g, char* l) {
  __builtin_amdgcn_global_load_lds((const __attribute__((address_space(1))) void*)g,
                                   (__attribute__((address_space(3))) void*)l, 16, 0, 0);
}

__device__ inline void cvt_store8(const float* __restrict__ s, bf16* d) {
  float4 x = ((const float4*)s)[0];
  float4 y = ((const float4*)s)[1];
  bf16x8 o;
  o[0] = (bf16)x.x; o[1] = (bf16)x.y; o[2] = (bf16)x.z; o[3] = (bf16)x.w;
  o[4] = (bf16)y.x; o[5] = (bf16)y.y; o[6] = (bf16)y.z; o[7] = (bf16)y.w;
  *(bf16x8*)d = o;
}

// ---------------- kernel 1: merged pre-pass ----------------
// blocks [0,1024): HWT_T[b][l*256+e][m] = sum_d H[b][m][l][d]*W[e][d]  (bf16)
// blocks [1024,3072): A fp32 -> bf16 grid-stride convert
__global__ __launch_bounds__(256) void pre_kernel(const float* __restrict__ H,
                                                  const float* __restrict__ Wm,
                                                  const float* __restrict__ A,
                                                  bf16* __restrict__ outT,
                                                  bf16* __restrict__ a16) {
  __shared__ __attribute__((aligned(16))) bf16 Ah[128 * 64];
  __shared__ __attribute__((aligned(16))) bf16 Wt[128 * 64];

  if (blockIdx.x >= 1024) {
    // ---- cvt role ----
    const int n8 = (int)((size_t)B_ * N_ * N_ / 8);
    int i = (blockIdx.x - 1024) * 256 + threadIdx.x;
    for (; i < n8; i += 2048 * 256) {
      const float4* s = (const float4*)A + (size_t)i * 2;
      float4 x = s[0], y = s[1];
      bf16x8 o;
      o[0] = (bf16)x.x; o[1] = (bf16)x.y; o[2] = (bf16)x.z; o[3] = (bf16)x.w;
      o[4] = (bf16)y.x; o[5] = (bf16)y.y; o[6] = (bf16)y.z; o[7] = (bf16)y.w;
      *(bf16x8*)(a16 + (size_t)i * 8) = o;
    }
    return;
  }

  // ---- hwt role ----
  const int bid = blockIdx.x;
  const int b   = bid >> 7;
  const int rem = bid & 127;
  const int te  = rem & 1;
  const int tr  = rem >> 1;
  const int r0  = tr * 128;
  const int e0  = te * 128;

  const int t    = threadIdx.x;
  const int lane = t & 63;
  const int wave = t >> 6;
  const int wr = wave >> 1, wc = wave & 1;

  const f32x4 zero = {0.f, 0.f, 0.f, 0.f};
  f32x4 acc[4][4];
  for (int m = 0; m < 4; ++m)
    for (int n = 0; n < 4; ++n) acc[m][n] = zero;

  const float* Hb = H + (size_t)b * (N_ * L_ * D_);
  const int mrow = t >> 3;
  const int colb = (t & 7) * 8;

  for (int k0 = 0; k0 < D_; k0 += 64) {
#pragma unroll
    for (int i = 0; i < 4; ++i) {
      const int r_local = mrow * 4 + i;     // l = i, m_local = mrow
      cvt_store8(Hb + (size_t)(r0 + r_local) * D_ + k0 + colb,
                 Ah + (size_t)t * 8 + i * 2048);
      const int erow = i * 32 + mrow;
      cvt_store8(Wm + (size_t)(e0 + erow) * D_ + k0 + colb,
                 Wt + (size_t)t * 8 + i * 2048);
    }
    __syncthreads();
#pragma unroll
    for (int kk = 0; kk < 2; ++kk) {
      bf16x8 af[4], bg[4];
#pragma unroll
      for (int m = 0; m < 4; ++m)
        af[m] = *(const bf16x8*)&Ah[(wr * 64 + m * 16 + (lane & 15)) * 64 + kk * 32 + (lane >> 4) * 8];
#pragma unroll
      for (int n = 0; n < 4; ++n)
        bg[n] = *(const bf16x8*)&Wt[(wc * 64 + n * 16 + (lane & 15)) * 64 + kk * 32 + (lane >> 4) * 8];
#pragma unroll
      for (int m = 0; m < 4; ++m)
#pragma unroll
        for (int n = 0; n < 4; ++n)
          acc[m][n] = __builtin_amdgcn_mfma_f32_16x16x32_bf16(af[m], bg[n], acc[m][n], 0, 0, 0);
    }
    __syncthreads();
  }

  bf16* ob = outT + (size_t)b * (LD_ * N_);
  const int m0 = tr * 32;
#pragma unroll
  for (int m16 = 0; m16 < 4; ++m16) {
    const int qrow = wr * 64 + m16 * 16 + ((lane >> 4) << 2);
    const int l  = qrow >> 5;
    const int ml = qrow & 31;
#pragma unroll
    for (int n = 0; n < 4; ++n) {
      const int e = e0 + wc * 64 + n * 16 + (lane & 15);
      bf16x4 v;
      v[0] = (bf16)acc[m16][n][0]; v[1] = (bf16)acc[m16][n][1];
      v[2] = (bf16)acc[m16][n][2]; v[3] = (bf16)acc[m16][n][3];
      *(bf16x4*)&ob[(size_t)(l * 256 + e) * N_ + m0 + ml] = v;
    }
  }
}

// ---------------- kernel 2: pipelined 256x256-tile 8-phase GEMM ----------------
// out[b][n][c] = relu(sum_m A16[b][n][m] * HWT[b][c][m] + bias[c&255])
__global__ __launch_bounds__(512, 2) void gemm8p_kernel(
    const bf16* __restrict__ A16, const bf16* __restrict__ HWT,
    const float* __restrict__ bias, float* __restrict__ out) {

  __shared__ __attribute__((aligned(128))) char smem[131072];

  // T1: 256 blocks % 8 == 0 -> xcd = batch
  const int bid = blockIdx.x;
  const int lg  = (bid & 7) * 32 + (bid >> 3);
  const int b   = lg >> 5;
  const int tn  = (lg >> 2) & 7;   // M tile (output rows, n-dim)
  const int tc  = lg & 3;          // N tile (output cols, c-dim)
  const int n0  = tn * 256;
  const int c0  = tc * 256;

  const int t    = threadIdx.x;
  const int lane = t & 63;
  const int w    = t >> 6;
  const int wm   = w >> 2;   // 0..1
  const int wn   = w & 3;    // 0..3
  const int l15  = lane & 15;
  const int cg   = lane >> 4;
  const int sl0  = cg ^ (lane & 7);     // swizzled 16B-slot for kk=0

  const char* Ab = (const char*)(A16 + (size_t)b * N_ * N_);
  const char* Hb = (const char*)(HWT + (size_t)b * LD_ * N_);
  const int  grow  = t >> 3;                       // 0..63
  const int  gslot = ((t & 7) ^ (grow & 7)) << 4;  // pre-swizzled source slot
  const char* pA = Ab + (size_t)(n0 + grow) * (N_ * 2) + gslot;
  const char* pB = Hb + (size_t)(c0 + grow) * (N_ * 2) + gslot;
  char* lbase = (char*)smem + t * 16;

#define STAGE(buf, isB, half, kt) do {                                        \
    const char* gp_ = ((isB) ? pB : pA) + (size_t)((half) * 128) * (N_ * 2)   \
                      + (size_t)(kt) * (BK * 2);                              \
    char* lp_ = lbase + (buf) * 65536 + (isB) * 32768 + (half) * 16384;       \
    gl16(gp_, lp_);                                                           \
    gl16(gp_ + (size_t)64 * (N_ * 2), lp_ + 8192);                            \
  } while (0)

#define LDA(buf, mh, fm, kk)                                                  \
  (*(const bf16x8*)(smem + (buf) * 65536 +                                    \
      (wm * 128 + (mh) * 64 + (fm) * 16 + l15) * 128 +                        \
      ((sl0 ^ ((kk) * 4)) << 4)))

#define LDB(buf, fn, kk)                                                      \
  (*(const bf16x8*)(smem + (buf) * 65536 + 32768 +                            \
      (wn * 64 + (fn) * 16 + l15) * 128 +                                     \
      ((sl0 ^ ((kk) * 4)) << 4)))

#define MFMA16(base, AF, BF)                                                  \
  do {                                                                        \
    __builtin_amdgcn_s_setprio(1);                                            \
    _Pragma("unroll")                                                         \
    for (int fm_ = 0; fm_ < 4; ++fm_)                                         \
      _Pragma("unroll")                                                       \
      for (int fn_ = 0; fn_ < 4; ++fn_)                                       \
        acc[(base) + fm_][fn_] = __builtin_amdgcn_mfma_f32_16x16x32_bf16(     \
            AF[fm_], BF[fn_], acc[(base) + fm_][fn_], 0, 0, 0);               \
    __builtin_amdgcn_s_setprio(0);                                            \
  } while (0)

#define BARRIER() do { __builtin_amdgcn_s_barrier();                          \
                       asm volatile("" ::: "memory"); } while (0)
#define VMCNT0_BAR() do {                                                     \
    asm volatile("s_waitcnt vmcnt(0)" ::: "memory");                          \
    __builtin_amdgcn_sched_barrier(0);                                        \
    BARRIER(); } while (0)

  f32x4 acc[8][4];
#pragma unroll
  for (int i_ = 0; i_ < 8; ++i_)
#pragma unroll
    for (int j_ = 0; j_ < 4; ++j_) acc[i_][j_] = (f32x4){0.f, 0.f, 0.f, 0.f};

  bf16x8 aX[4], aY[4], bA[4], bB[4];

  // prologue: buf0 <- kt0 fully; then initial frag reads (feed P1's MFMA)
  STAGE(0, 0, 0, 0); STAGE(0, 0, 1, 0); STAGE(0, 1, 0, 0); STAGE(0, 1, 1, 0);
  VMCNT0_BAR();
#pragma unroll
  for (int fm = 0; fm < 4; ++fm) aY[fm] = LDA(0, 0, fm, 0);
#pragma unroll
  for (int fn = 0; fn < 4; ++fn) bA[fn] = LDB(0, fn, 0);

#pragma unroll 1
  for (int i = 0; i < NI; ++i) {
    const int kt1 = 2 * i + 1;
    const int kt2 = (2 * i + 2 < NT) ? 2 * i + 2 : NT - 2;  // clamp: tail stage unused

    // P1: reads aX<-A(b0,mh0,kk1), bB<-B(b0,kk1); stage buf1<-kt1 (A0,A1,B0);
    //     MFMA(mh0,kk0) = aY x bA
#pragma unroll
    for (int fm = 0; fm < 4; ++fm) aX[fm] = LDA(0, 0, fm, 1);
#pragma unroll
    for (int fn = 0; fn < 4; ++fn) bB[fn] = LDB(0, fn, 1);
    STAGE(1, 0, 0, kt1); STAGE(1, 0, 1, kt1); STAGE(1, 1, 0, kt1);
    MFMA16(0, aY, bA);

    // P2: reads aY<-A(b0,mh1,kk0); stage buf1.B1; MFMA(mh0,kk1) = aX x bB
#pragma unroll
    for (int fm = 0; fm < 4; ++fm) aY[fm] = LDA(0, 1, fm, 0);
    STAGE(1, 1, 1, kt1);
    MFMA16(0, aX, bB);

    // P3: reads aX<-A(b0,mh1,kk1); MFMA(mh1,kk0) = aY x bA; [buf1 ready] vmcnt0+BAR
#pragma unroll
    for (int fm = 0; fm < 4; ++fm) aX[fm] = LDA(0, 1, fm, 1);
    MFMA16(4, aY, bA);
    VMCNT0_BAR();

    // P4: reads aY<-A(b1,mh0,kk0), bA<-B(b1,kk0); MFMA(mh1,kk1) = aX x bB;
    //     BAR (buf0 reads all retired -> P5 may re-stage buf0)
#pragma unroll
    for (int fm = 0; fm < 4; ++fm) aY[fm] = LDA(1, 0, fm, 0);
#pragma unroll
    for (int fn = 0; fn < 4; ++fn) bA[fn] = LDB(1, fn, 0);
    MFMA16(4, aX, bB);
    BARRIER();

    // P5: reads aX<-A(b1,mh0,kk1), bB<-B(b1,kk1); stage buf0<-kt2 (A0,A1,B0);
    //     MFMA(mh0,kk0) = aY x bA
#pragma unroll
    for (int fm = 0; fm < 4; ++fm) aX[fm] = LDA(1, 0, fm, 1);
#pragma unroll
    for (int fn = 0; fn < 4; ++fn) bB[fn] = LDB(1, fn, 1);
    STAGE(0, 0, 0, kt2); STAGE(0, 0, 1, kt2); STAGE(0, 1, 0, kt2);
    MFMA16(0, aY, bA);

    // P6: reads aY<-A(b1,mh1,kk0); stage buf0.B1; MFMA(mh0,kk1) = aX x bB
#pragma unroll
    for (int fm = 0; fm < 4; ++fm) aY[fm] = LDA(1, 1, fm, 0);
    STAGE(0, 1, 1, kt2);
    MFMA16(0, aX, bB);

    // P7: reads aX<-A(b1,mh1,kk1); MFMA(mh1,kk0) = aY x bA; [buf0 ready] vmcnt0+BAR
#pragma unroll
    for (int fm = 0; fm < 4; ++fm) aX[fm] = LDA(1, 1, fm, 1);
    MFMA16(4, aY, bA);
    VMCNT0_BAR();

    // P8: reads aY<-A(b0new,mh0,kk0), bA<-B(b0new,kk0); MFMA(mh1,kk1) = aX x bB;
    //     BAR (buf1 reads all retired -> next P1 may re-stage buf1)
#pragma unroll
    for (int fm = 0; fm < 4; ++fm) aY[fm] = LDA(0, 0, fm, 0);
#pragma unroll
    for (int fn = 0; fn < 4; ++fn) bA[fn] = LDB(0, fn, 0);
    MFMA16(4, aX, bB);
    BARRIER();
  }

  // epilogue: + bias, relu, fp32 store
  float* ob = out + (size_t)b * N_ * LD_;
  const int orow0 = n0 + wm * 128 + cg * 4;
  const int ocol0 = c0 + wn * 64 + l15;
#pragma unroll
  for (int mh = 0; mh < 2; ++mh)
#pragma unroll
    for (int fm = 0; fm < 4; ++fm) {
      const int r = orow0 + mh * 64 + fm * 16;
#pragma unroll
      for (int fn = 0; fn < 4; ++fn) {
        const int c = ocol0 + fn * 16;
        const float bv = bias[c & 255];
        const f32x4 v = acc[mh * 4 + fm][fn];
#pragma unroll
        for (int j = 0; j < 4; ++j) {
          const float x = v[j] + bv;
          ob[(size_t)(r + j) * LD_ + c] = x > 0.f ? x : 0.f;
        }
      }
    }
#undef STAGE
#undef LDA
#undef LDB
#undef MFMA16
#undef BARRIER
#undef VMCNT0_BAR
}

extern "C" void kernel_launch(void* const* d_in, const int* in_sizes, int n_in,
                              void* d_out, int out_size, void* d_ws, size_t ws_size,
                              hipStream_t stream) {
  const float* H    = (const float*)d_in[0];   // prop_state (B,N,L,D)
  const float* A    = (const float*)d_in[1];   // (B,N,N)
  const float* Wm   = (const float*)d_in[2];   // (D,D)
  const float* bias = (const float*)d_in[3];   // (D,)
  float* out = (float*)d_out;

  const size_t hwt_bytes = (size_t)B_ * LD_ * N_ * sizeof(bf16);  // 33.5 MB
  const size_t a16_bytes = (size_t)B_ * N_ * N_ * sizeof(bf16);   // 67.1 MB
  if (ws_size < hwt_bytes + a16_bytes) return;  // ws proven sufficient in R1

  bf16* hwt = (bf16*)d_ws;
  bf16* a16 = (bf16*)((char*)d_ws + hwt_bytes);

  pre_kernel<<<dim3(3072), dim3(256), 0, stream>>>(H, Wm, A, hwt, a16);
  gemm8p_kernel<<<dim3(256), dim3(512), 0, stream>>>(a16, hwt, bias, out);
}